// Round 1
// baseline (615.719 us; speedup 1.0000x reference)
//
#include <hip/hip_runtime.h>

#define DFEAT 128        // feature dim (floats); 64 float2 per row
#define WPB   4          // waves per block in spmm (256 threads)
#define SCAN_B 1024

// ---------- tiny softmax over a_in[0..2] ----------
__global__ void softmax3_k(const float* __restrict__ a_in, float* __restrict__ a) {
  if (threadIdx.x == 0 && blockIdx.x == 0) {
    float x0 = a_in[0], x1 = a_in[1], x2 = a_in[2];
    float m = fmaxf(x0, fmaxf(x1, x2));
    float e0 = expf(x0 - m), e1 = expf(x1 - m), e2 = expf(x2 - m);
    float s = e0 + e1 + e2;
    a[0] = e0 / s; a[1] = e1 / s; a[2] = e2 / s;
  }
}

// ---------- edge histogram: row counts + rowsum(edge_val) ----------
__global__ void hist_k(const int* __restrict__ row, const float* __restrict__ val,
                       float* __restrict__ rowsum, int* __restrict__ cnt, int E) {
  int i = blockIdx.x * 256 + threadIdx.x;
  if (i < E) {
    int r = row[i];
    atomicAdd(&cnt[r], 1);
    atomicAdd(&rowsum[r], val[i]);
  }
}

// ---------- d^{-1/2} in place ----------
__global__ void dis_k(float* __restrict__ rowsum, int n) {
  int i = blockIdx.x * 256 + threadIdx.x;
  if (i < n) {
    float s = rowsum[i];
    rowsum[i] = (s > 0.0f) ? rsqrtf(s) : 0.0f;
  }
}

// ---------- scan stage A: per-block inclusive scan of cnt -> row_ptr[g], block sums ----------
__global__ void scanA_k(const int* __restrict__ cnt, int* __restrict__ incl,
                        int* __restrict__ bsum, int n) {
  __shared__ int tmp[SCAN_B];
  int tid = threadIdx.x;
  int g = blockIdx.x * SCAN_B + tid;
  tmp[tid] = (g < n) ? cnt[g] : 0;
  __syncthreads();
  for (int off = 1; off < SCAN_B; off <<= 1) {
    int t = (tid >= off) ? tmp[tid - off] : 0;
    __syncthreads();
    tmp[tid] += t;
    __syncthreads();
  }
  if (g < n) incl[g] = tmp[tid];
  if (tid == SCAN_B - 1) bsum[blockIdx.x] = tmp[tid];
}

// ---------- scan stage B: inclusive scan of block sums (single block, nb <= 128) ----------
__global__ void scanB_k(int* __restrict__ bsum, int nb) {
  __shared__ int tmp[128];
  int tid = threadIdx.x;
  tmp[tid] = (tid < nb) ? bsum[tid] : 0;
  __syncthreads();
  for (int off = 1; off < 128; off <<= 1) {
    int t = (tid >= off) ? tmp[tid - off] : 0;
    __syncthreads();
    tmp[tid] += t;
    __syncthreads();
  }
  if (tid < nb) bsum[tid] = tmp[tid];
}

// ---------- scan stage C: finalize row_ptr (exclusive starts) + init cursors ----------
__global__ void scanC_k(int* __restrict__ row_ptr /* holds incl for g<n */,
                        const int* __restrict__ cnt, const int* __restrict__ bsum,
                        int* __restrict__ cursor, int n) {
  int g = blockIdx.x * SCAN_B + threadIdx.x;
  if (g >= n) return;
  int off = (blockIdx.x > 0) ? bsum[blockIdx.x - 1] : 0;
  int incl = row_ptr[g] + off;
  int start = incl - cnt[g];
  row_ptr[g] = start;
  cursor[g]  = start;
  if (g == n - 1) row_ptr[n] = incl;   // == E
}

// ---------- covered mask ----------
__global__ void covered_k(const int* __restrict__ index, int* __restrict__ covered, int n) {
  int i = blockIdx.x * 256 + threadIdx.x;
  if (i < n) covered[index[i]] = 1;
}

// ---------- scatter edges into CSR order; pre-scale val by dis[col] ----------
__global__ void scatter_k(const int* __restrict__ row, const int* __restrict__ col,
                          const float* __restrict__ val, const float* __restrict__ dis,
                          int* __restrict__ cursor, int2* __restrict__ pairs, int E) {
  int i = blockIdx.x * 256 + threadIdx.x;
  if (i < E) {
    int r = row[i];
    int c = col[i];
    int p = atomicAdd(&cursor[r], 1);
    int2 pr;
    pr.x = c;
    pr.y = __float_as_int(val[i] * dis[c]);
    pairs[p] = pr;
  }
}

// ---------- SpMM: one wave per row, 64 lanes x float2 = 128 feats ----------
template <bool FIRST>
__global__ void spmm_k(const int* __restrict__ row_ptr,
                       const int2* __restrict__ pairs,
                       const float* __restrict__ dis,
                       const float2* __restrict__ h,     // input features [n*64]
                       const int* __restrict__ index,
                       const float2* __restrict__ feat,  // original features (FIRST only)
                       float2* __restrict__ hA,          // h1 buffer (FIRST only)
                       float2* __restrict__ out,
                       const float* __restrict__ a,
                       int n) {
  int wave = blockIdx.x * WPB + (threadIdx.x >> 6);
  if (wave >= n) return;
  int lane = threadIdx.x & 63;
  int beg = row_ptr[wave], end = row_ptr[wave + 1];
  float2 acc = make_float2(0.0f, 0.0f);
  for (int e = beg; e < end; ++e) {
    int2 p = pairs[e];
    float v = __int_as_float(p.y);
    float2 x = h[p.x * 64 + lane];
    acc.x = fmaf(v, x.x, acc.x);
    acc.y = fmaf(v, x.y, acc.y);
  }
  float disr = dis[wave];
  acc.x *= disr; acc.y *= disr;
  int idx = index[wave];
  int o = idx * 64 + lane;
  if (FIRST) {
    float a0 = a[0], a1 = a[1];
    float2 f = feat[o];
    hA[o] = acc;
    out[o] = make_float2(fmaf(a1, acc.x, a0 * f.x), fmaf(a1, acc.y, a0 * f.y));
  } else {
    float a2 = a[2];
    float2 r = out[o];
    out[o] = make_float2(fmaf(a2, acc.x, r.x), fmaf(a2, acc.y, r.y));
  }
}

// ---------- fixups for uncovered nodes (no-op when index is a permutation) ----------
__global__ void fixup1_k(const int* __restrict__ covered, const float2* __restrict__ feat,
                         float2* __restrict__ hA, float2* __restrict__ out,
                         const float* __restrict__ a, int n) {
  int v = blockIdx.x * 256 + threadIdx.x;
  if (v >= n || covered[v]) return;
  float c = a[0] + a[1];
  for (int d = 0; d < 64; ++d) {
    float2 f = feat[v * 64 + d];
    hA[v * 64 + d] = f;
    out[v * 64 + d] = make_float2(c * f.x, c * f.y);
  }
}

__global__ void fixup2_k(const int* __restrict__ covered, const float2* __restrict__ hA,
                         float2* __restrict__ out, const float* __restrict__ a, int n) {
  int v = blockIdx.x * 256 + threadIdx.x;
  if (v >= n || covered[v]) return;
  float a2 = a[2];
  for (int d = 0; d < 64; ++d) {
    float2 hh = hA[v * 64 + d];
    float2 r = out[v * 64 + d];
    out[v * 64 + d] = make_float2(fmaf(a2, hh.x, r.x), fmaf(a2, hh.y, r.y));
  }
}

extern "C" void kernel_launch(void* const* d_in, const int* in_sizes, int n_in,
                              void* d_out, int out_size, void* d_ws, size_t ws_size,
                              hipStream_t stream) {
  const float* features = (const float*)d_in[0];
  const int*   edge_row = (const int*)d_in[1];
  const int*   edge_col = (const int*)d_in[2];
  const float* edge_val = (const float*)d_in[3];
  const int*   index    = (const int*)d_in[4];
  const float* a_in     = (const float*)d_in[5];

  const int E = in_sizes[1];
  const int N = in_sizes[4];

  float* out = (float*)d_out;

  // ---- workspace carve (256B aligned) ----
  char* ws = (char*)d_ws;
  size_t off = 0;
  auto carve = [&](size_t bytes) -> char* {
    char* p = ws + off;
    off = (off + bytes + 255) & ~(size_t)255;
    return p;
  };
  float* a_buf   = (float*)carve(16 * sizeof(float));
  // zero region: rowsum | cnt | covered, contiguous for one memset
  char*  zbase   = carve((size_t)3 * N * sizeof(int));
  float* rowsum  = (float*)zbase;                 // becomes dis in place
  int*   cnt     = (int*)(zbase + (size_t)N * 4);
  int*   covered = (int*)(zbase + (size_t)2 * N * 4);
  int*   row_ptr = (int*)carve((size_t)(N + 1) * sizeof(int));
  int*   cursor  = (int*)carve((size_t)N * sizeof(int));
  int*   bsum    = (int*)carve(256 * sizeof(int));
  int2*  pairs   = (int2*)carve((size_t)E * sizeof(int2));
  float2* hA     = (float2*)carve((size_t)N * (DFEAT / 2) * sizeof(float2));
  (void)ws_size; (void)n_in; (void)out_size;

  const int nbE = (E + 255) / 256;
  const int nbN = (N + 255) / 256;
  const int nbScan = (N + SCAN_B - 1) / SCAN_B;

  hipMemsetAsync(zbase, 0, (size_t)3 * N * sizeof(int), stream);
  softmax3_k<<<1, 64, 0, stream>>>(a_in, a_buf);
  hist_k<<<nbE, 256, 0, stream>>>(edge_row, edge_val, rowsum, cnt, E);
  dis_k<<<nbN, 256, 0, stream>>>(rowsum, N);
  scanA_k<<<nbScan, SCAN_B, 0, stream>>>(cnt, row_ptr, bsum, N);
  scanB_k<<<1, 128, 0, stream>>>(bsum, nbScan);
  scanC_k<<<nbScan, SCAN_B, 0, stream>>>(row_ptr, cnt, bsum, cursor, N);
  covered_k<<<nbN, 256, 0, stream>>>(index, covered, N);
  scatter_k<<<nbE, 256, 0, stream>>>(edge_row, edge_col, edge_val, rowsum,
                                     cursor, pairs, E);

  const int nbSpmm = (N + WPB - 1) / WPB;
  // layer 1: out = a0*features + a1*h1 ; hA = h1
  spmm_k<true><<<nbSpmm, WPB * 64, 0, stream>>>(
      row_ptr, pairs, rowsum, (const float2*)features, index,
      (const float2*)features, hA, (float2*)out, a_buf, N);
  fixup1_k<<<nbN, 256, 0, stream>>>(covered, (const float2*)features, hA,
                                    (float2*)out, a_buf, N);
  // layer 2: out += a2*h2 (h2 scattered rows fused into the write)
  spmm_k<false><<<nbSpmm, WPB * 64, 0, stream>>>(
      row_ptr, pairs, rowsum, (const float2*)hA, index,
      nullptr, nullptr, (float2*)out, a_buf, N);
  fixup2_k<<<nbN, 256, 0, stream>>>(covered, (const float2*)hA,
                                    (float2*)out, a_buf, N);
}

// Round 2
// 397.910 us; speedup vs baseline: 1.5474x; 1.5474x over previous
//
#include <hip/hip_runtime.h>

#define WPB   4          // waves per block in spmm (256 threads)
#define SCAN_B 1024

// ---------- bf16 helpers ----------
__device__ __forceinline__ unsigned bf16rne(float x) {
  unsigned u = __float_as_uint(x);
  return (u + 0x7fffu + ((u >> 16) & 1u)) >> 16;
}
__device__ __forceinline__ float bf_lo(unsigned g) { return __uint_as_float(g << 16); }
__device__ __forceinline__ float bf_hi(unsigned g) { return __uint_as_float(g & 0xffff0000u); }

// ---------- tiny softmax over a_in[0..2] ----------
__global__ void softmax3_k(const float* __restrict__ a_in, float* __restrict__ a) {
  if (threadIdx.x == 0 && blockIdx.x == 0) {
    float x0 = a_in[0], x1 = a_in[1], x2 = a_in[2];
    float m = fmaxf(x0, fmaxf(x1, x2));
    float e0 = expf(x0 - m), e1 = expf(x1 - m), e2 = expf(x2 - m);
    float s = e0 + e1 + e2;
    a[0] = e0 / s; a[1] = e1 / s; a[2] = e2 / s;
  }
}

// ---------- edge histogram + covered mask ----------
__global__ void hist_cov_k(const int* __restrict__ row, const float* __restrict__ val,
                           const int* __restrict__ index, float* __restrict__ rowsum,
                           int* __restrict__ cnt, int* __restrict__ covered, int E, int n) {
  int i = blockIdx.x * 256 + threadIdx.x;
  if (i < E) {
    int r = row[i];
    atomicAdd(&cnt[r], 1);
    atomicAdd(&rowsum[r], val[i]);
  }
  if (i < n) covered[index[i]] = 1;
}

// ---------- fp32 -> packed bf16 feature table ----------
__global__ void tobf16_k(const float2* __restrict__ f, unsigned* __restrict__ hb, int nw) {
  int i = blockIdx.x * 256 + threadIdx.x;
  if (i < nw) {
    float2 v = f[i];
    hb[i] = bf16rne(v.x) | (bf16rne(v.y) << 16);
  }
}

// ---------- scan stage A ----------
__global__ void scanA_k(const int* __restrict__ cnt, int* __restrict__ incl,
                        int* __restrict__ bsum, int n) {
  __shared__ int tmp[SCAN_B];
  int tid = threadIdx.x;
  int g = blockIdx.x * SCAN_B + tid;
  tmp[tid] = (g < n) ? cnt[g] : 0;
  __syncthreads();
  for (int off = 1; off < SCAN_B; off <<= 1) {
    int t = (tid >= off) ? tmp[tid - off] : 0;
    __syncthreads();
    tmp[tid] += t;
    __syncthreads();
  }
  if (g < n) incl[g] = tmp[tid];
  if (tid == SCAN_B - 1) bsum[blockIdx.x] = tmp[tid];
}

// ---------- scan stage B (single block, nb <= 128) ----------
__global__ void scanB_k(int* __restrict__ bsum, int nb) {
  __shared__ int tmp[128];
  int tid = threadIdx.x;
  tmp[tid] = (tid < nb) ? bsum[tid] : 0;
  __syncthreads();
  for (int off = 1; off < 128; off <<= 1) {
    int t = (tid >= off) ? tmp[tid - off] : 0;
    __syncthreads();
    tmp[tid] += t;
    __syncthreads();
  }
  if (tid < nb) bsum[tid] = tmp[tid];
}

// ---------- scan stage C: row_ptr <- exclusive start; also dis = rowsum^-1/2 ----------
// scatter's atomics then push row_ptr[g] to the row END; spmm reads
// beg = (g ? row_ptr[g-1] : 0), end = row_ptr[g].
__global__ void scanC_k(int* __restrict__ row_ptr, const int* __restrict__ cnt,
                        const int* __restrict__ bsum, float* __restrict__ rowsum, int n) {
  int g = blockIdx.x * SCAN_B + threadIdx.x;
  if (g >= n) return;
  int off = (blockIdx.x > 0) ? bsum[blockIdx.x - 1] : 0;
  int incl = row_ptr[g] + off;
  row_ptr[g] = incl - cnt[g];
  float s = rowsum[g];
  rowsum[g] = (s > 0.0f) ? rsqrtf(s) : 0.0f;
}

// ---------- scatter edges into CSR order; pre-scale val by dis[col] ----------
__global__ void scatter_k(const int* __restrict__ row, const int* __restrict__ col,
                          const float* __restrict__ val, const float* __restrict__ dis,
                          int* __restrict__ row_ptr, int2* __restrict__ pairs, int E) {
  int i = blockIdx.x * 256 + threadIdx.x;
  if (i < E) {
    int r = row[i];
    int c = col[i];
    int p = atomicAdd(&row_ptr[r], 1);
    int2 pr;
    pr.x = c;
    pr.y = __float_as_int(val[i] * dis[c]);
    pairs[p] = pr;
  }
}

// ---------- shared SpMM row body: returns dis[row]*sum(vals*h[col]) in acc ----------
#define SPMM_BODY(HSRC)                                                        \
  float ax0 = 0.f, ay0 = 0.f, ax1 = 0.f, ay1 = 0.f;                            \
  for (int base = beg; base < end; base += 64) {                               \
    int m = end - base; if (m > 64) m = 64;                                    \
    int2 p = make_int2(0, 0);                                                  \
    if (base + lane < end) p = pairs[base + lane];                             \
    int pc = p.x; float pv = __int_as_float(p.y);                              \
    int j = 0;                                                                 \
    for (; j + 4 <= m; j += 4) {                                               \
      int   c0 = __shfl(pc, j),     c1 = __shfl(pc, j + 1);                    \
      int   c2 = __shfl(pc, j + 2), c3 = __shfl(pc, j + 3);                    \
      float v0 = __shfl(pv, j),     v1 = __shfl(pv, j + 1);                    \
      float v2 = __shfl(pv, j + 2), v3 = __shfl(pv, j + 3);                    \
      unsigned g0 = HSRC[(size_t)c0 * 64 + lane];                              \
      unsigned g1 = HSRC[(size_t)c1 * 64 + lane];                              \
      unsigned g2 = HSRC[(size_t)c2 * 64 + lane];                              \
      unsigned g3 = HSRC[(size_t)c3 * 64 + lane];                              \
      ax0 = fmaf(v0, bf_lo(g0), ax0); ay0 = fmaf(v0, bf_hi(g0), ay0);          \
      ax1 = fmaf(v1, bf_lo(g1), ax1); ay1 = fmaf(v1, bf_hi(g1), ay1);          \
      ax0 = fmaf(v2, bf_lo(g2), ax0); ay0 = fmaf(v2, bf_hi(g2), ay0);          \
      ax1 = fmaf(v3, bf_lo(g3), ax1); ay1 = fmaf(v3, bf_hi(g3), ay1);          \
    }                                                                          \
    for (; j < m; ++j) {                                                       \
      int c = __shfl(pc, j); float v = __shfl(pv, j);                          \
      unsigned g = HSRC[(size_t)c * 64 + lane];                                \
      ax0 = fmaf(v, bf_lo(g), ax0); ay0 = fmaf(v, bf_hi(g), ay0);              \
    }                                                                          \
  }

// ---------- layer 1: hA[index[r]] = bf16( dis[r] * sum vals*hB[col] ) ----------
__global__ void spmm1_k(const int* __restrict__ row_ptr, const int2* __restrict__ pairs,
                        const float* __restrict__ dis, const unsigned* __restrict__ hB,
                        const int* __restrict__ index, unsigned* __restrict__ hA, int n) {
  int wave = blockIdx.x * WPB + (threadIdx.x >> 6);
  if (wave >= n) return;
  int lane = threadIdx.x & 63;
  int end = row_ptr[wave];
  int beg = wave ? row_ptr[wave - 1] : 0;
  SPMM_BODY(hB)
  float dr = dis[wave];
  float x = (ax0 + ax1) * dr, y = (ay0 + ay1) * dr;
  hA[(size_t)index[wave] * 64 + lane] = bf16rne(x) | (bf16rne(y) << 16);
}

// ---------- layer 2 fused epilogue: out[o] = a0*f[o] + a1*hA[o] + a2*acc ----------
__global__ void spmm2_k(const int* __restrict__ row_ptr, const int2* __restrict__ pairs,
                        const float* __restrict__ dis, const unsigned* __restrict__ hA,
                        const int* __restrict__ index, const float2* __restrict__ feat,
                        float2* __restrict__ out, const float* __restrict__ a, int n) {
  int wave = blockIdx.x * WPB + (threadIdx.x >> 6);
  if (wave >= n) return;
  int lane = threadIdx.x & 63;
  int end = row_ptr[wave];
  int beg = wave ? row_ptr[wave - 1] : 0;
  SPMM_BODY(hA)
  float dr = dis[wave];
  float hx = (ax0 + ax1) * dr, hy = (ay0 + ay1) * dr;
  size_t o = (size_t)index[wave] * 64 + lane;
  unsigned g = hA[o];
  float2 f = feat[o];
  float a0 = a[0], a1 = a[1], a2 = a[2];
  out[o] = make_float2(fmaf(a2, hx, fmaf(a1, bf_lo(g), a0 * f.x)),
                       fmaf(a2, hy, fmaf(a1, bf_hi(g), a0 * f.y)));
}

// ---------- fixups for uncovered nodes (no-op when index is a permutation) ----------
__global__ void fixup1_k(const int* __restrict__ covered, const unsigned* __restrict__ hB,
                         unsigned* __restrict__ hA, int n) {
  int v = blockIdx.x * 256 + threadIdx.x;
  if (v >= n || covered[v]) return;
  for (int d = 0; d < 64; ++d) hA[(size_t)v * 64 + d] = hB[(size_t)v * 64 + d];
}

__global__ void fixup2_k(const int* __restrict__ covered, const float2* __restrict__ feat,
                         float2* __restrict__ out, const float* __restrict__ a, int n) {
  int v = blockIdx.x * 256 + threadIdx.x;
  if (v >= n || covered[v]) return;
  float s = a[0] + a[1] + a[2];
  for (int d = 0; d < 64; ++d) {
    float2 f = feat[(size_t)v * 64 + d];
    out[(size_t)v * 64 + d] = make_float2(s * f.x, s * f.y);
  }
}

extern "C" void kernel_launch(void* const* d_in, const int* in_sizes, int n_in,
                              void* d_out, int out_size, void* d_ws, size_t ws_size,
                              hipStream_t stream) {
  const float* features = (const float*)d_in[0];
  const int*   edge_row = (const int*)d_in[1];
  const int*   edge_col = (const int*)d_in[2];
  const float* edge_val = (const float*)d_in[3];
  const int*   index    = (const int*)d_in[4];
  const float* a_in     = (const float*)d_in[5];

  const int E = in_sizes[1];
  const int N = in_sizes[4];

  float* out = (float*)d_out;

  // ---- workspace carve (256B aligned) ----
  char* ws = (char*)d_ws;
  size_t off = 0;
  auto carve = [&](size_t bytes) -> char* {
    char* p = ws + off;
    off = (off + bytes + 255) & ~(size_t)255;
    return p;
  };
  float* a_buf   = (float*)carve(16 * sizeof(float));
  char*  zbase   = carve((size_t)3 * N * sizeof(int));   // rowsum | cnt | covered
  float* rowsum  = (float*)zbase;                        // becomes dis in place
  int*   cnt     = (int*)(zbase + (size_t)N * 4);
  int*   covered = (int*)(zbase + (size_t)2 * N * 4);
  int*   row_ptr = (int*)carve((size_t)N * sizeof(int));
  int*   bsum    = (int*)carve(256 * sizeof(int));
  int2*  pairs   = (int2*)carve((size_t)E * sizeof(int2));
  unsigned* hA   = (unsigned*)carve((size_t)N * 64 * sizeof(unsigned)); // bf16 h1
  unsigned* hB   = (unsigned*)carve((size_t)N * 64 * sizeof(unsigned)); // bf16 feat
  (void)ws_size; (void)n_in; (void)out_size;

  const int nbE = (E + 255) / 256;
  const int nbW = (N * 64 + 255) / 256;
  const int nbScan = (N + SCAN_B - 1) / SCAN_B;
  const int nbN = (N + 255) / 256;

  hipMemsetAsync(zbase, 0, (size_t)3 * N * sizeof(int), stream);
  softmax3_k<<<1, 64, 0, stream>>>(a_in, a_buf);
  tobf16_k<<<nbW, 256, 0, stream>>>((const float2*)features, hB, N * 64);
  hist_cov_k<<<nbE, 256, 0, stream>>>(edge_row, edge_val, index, rowsum, cnt,
                                      covered, E, N);
  scanA_k<<<nbScan, SCAN_B, 0, stream>>>(cnt, row_ptr, bsum, N);
  scanB_k<<<1, 128, 0, stream>>>(bsum, nbScan);
  scanC_k<<<nbScan, SCAN_B, 0, stream>>>(row_ptr, cnt, bsum, rowsum, N);
  scatter_k<<<nbE, 256, 0, stream>>>(edge_row, edge_col, edge_val, rowsum,
                                     row_ptr, pairs, E);

  const int nbSpmm = (N + WPB - 1) / WPB;
  spmm1_k<<<nbSpmm, WPB * 64, 0, stream>>>(row_ptr, pairs, rowsum, hB, index, hA, N);
  fixup1_k<<<nbN, 256, 0, stream>>>(covered, hB, hA, N);
  spmm2_k<<<nbSpmm, WPB * 64, 0, stream>>>(row_ptr, pairs, rowsum, hA, index,
                                           (const float2*)features, (float2*)out,
                                           a_buf, N);
  fixup2_k<<<nbN, 256, 0, stream>>>(covered, (const float2*)features,
                                    (float2*)out, a_buf, N);
}

// Round 3
// 235.668 us; speedup vs baseline: 2.6127x; 1.6884x over previous
//
#include <hip/hip_runtime.h>

#define WPB    4         // waves per block in spmm (256 threads)
#define SCAN_B 1024
#define P1B    256       // blocks in bucketing passes
#define BKT_SH 8         // 256 rows per bucket

// ---------- bf16 helpers ----------
__device__ __forceinline__ unsigned bf16rne(float x) {
  unsigned u = __float_as_uint(x);
  return (u + 0x7fffu + ((u >> 16) & 1u)) >> 16;
}
__device__ __forceinline__ float bf_lo(unsigned g) { return __uint_as_float(g << 16); }
__device__ __forceinline__ float bf_hi(unsigned g) { return __uint_as_float(g & 0xffff0000u); }

// ---------- tiny softmax over a_in[0..2] ----------
__global__ void softmax3_k(const float* __restrict__ a_in, float* __restrict__ a) {
  if (threadIdx.x == 0 && blockIdx.x == 0) {
    float x0 = a_in[0], x1 = a_in[1], x2 = a_in[2];
    float m = fmaxf(x0, fmaxf(x1, x2));
    float e0 = expf(x0 - m), e1 = expf(x1 - m), e2 = expf(x2 - m);
    float s = e0 + e1 + e2;
    a[0] = e0 / s; a[1] = e1 / s; a[2] = e2 / s;
  }
}

// ---------- fp32 -> packed bf16 feature table ----------
__global__ void tobf16_k(const float2* __restrict__ f, unsigned* __restrict__ hb, int nw) {
  int i = blockIdx.x * 256 + threadIdx.x;
  if (i < nw) {
    float2 v = f[i];
    hb[i] = bf16rne(v.x) | (bf16rne(v.y) << 16);
  }
}

// ---------- pass 1: per-(bucket,block) edge histogram, LDS atomics only ----------
__global__ void p1_k(const int* __restrict__ row, int* __restrict__ bhist,
                     int E, int C, int NB) {
  extern __shared__ int h[];
  for (int k = threadIdx.x; k < NB; k += 256) h[k] = 0;
  __syncthreads();
  int s = blockIdx.x * C, e = min(E, s + C);
  for (int i = s + threadIdx.x; i < e; i += 256)
    atomicAdd(&h[row[i] >> BKT_SH], 1);
  __syncthreads();
  for (int k = threadIdx.x; k < NB; k += 256)
    bhist[(size_t)k * P1B + blockIdx.x] = h[k];
}

// ---------- scan stage A over bhist ----------
__global__ void scanA_k(const int* __restrict__ cnt, int* __restrict__ incl,
                        int* __restrict__ bsum, int n) {
  __shared__ int tmp[SCAN_B];
  int tid = threadIdx.x;
  int g = blockIdx.x * SCAN_B + tid;
  tmp[tid] = (g < n) ? cnt[g] : 0;
  __syncthreads();
  for (int off = 1; off < SCAN_B; off <<= 1) {
    int t = (tid >= off) ? tmp[tid - off] : 0;
    __syncthreads();
    tmp[tid] += t;
    __syncthreads();
  }
  if (g < n) incl[g] = tmp[tid];
  if (tid == SCAN_B - 1) bsum[blockIdx.x] = tmp[tid];
}

// ---------- scan stage B (single block, nb <= 128) ----------
__global__ void scanB_k(int* __restrict__ bsum, int nb) {
  __shared__ int tmp[128];
  int tid = threadIdx.x;
  tmp[tid] = (tid < nb) ? bsum[tid] : 0;
  __syncthreads();
  for (int off = 1; off < 128; off <<= 1) {
    int t = (tid >= off) ? tmp[tid - off] : 0;
    __syncthreads();
    tmp[tid] += t;
    __syncthreads();
  }
  if (tid < nb) bsum[tid] = tmp[tid];
}

// ---------- scan stage C: boffs <- exclusive (in place over incl) ----------
__global__ void scanC_k(int* __restrict__ boffs, const int* __restrict__ bhist,
                        const int* __restrict__ bsum, int n) {
  int g = blockIdx.x * SCAN_B + threadIdx.x;
  if (g >= n) return;
  int off = (blockIdx.x > 0) ? bsum[blockIdx.x - 1] : 0;
  boffs[g] = boffs[g] + off - bhist[g];
}

// ---------- pass 2: scatter edges into bucket-grouped order (LDS cursors) ----------
__global__ void p2_k(const int* __restrict__ row, const int* __restrict__ col,
                     const float* __restrict__ val, const int* __restrict__ boffs,
                     int2* __restrict__ bedge, int E, int C, int NB) {
  extern __shared__ int cur[];
  for (int k = threadIdx.x; k < NB; k += 256)
    cur[k] = boffs[(size_t)k * P1B + blockIdx.x];
  __syncthreads();
  int s = blockIdx.x * C, e = min(E, s + C);
  for (int i = s + threadIdx.x; i < e; i += 256) {
    int r = row[i];
    int p = atomicAdd(&cur[r >> BKT_SH], 1);
    bedge[p] = make_int2(((r & 255) << 24) | col[i], __float_as_int(val[i]));
  }
}

// ---------- pass 3: per-bucket counting sort by row + rowsum + row_start ----------
__global__ void p3_k(const int2* __restrict__ bedge, const int* __restrict__ boffs,
                     int* __restrict__ row_start, float* __restrict__ rowsum,
                     int2* __restrict__ pairs, int E, int N, int NB) {
  __shared__ int rcnt[256];
  __shared__ float rsum[256];
  __shared__ int rbase[256];
  __shared__ int tmp[256];
  int kb = blockIdx.x, t = threadIdx.x;
  int base = boffs[(size_t)kb * P1B];
  int end  = (kb + 1 < NB) ? boffs[(size_t)(kb + 1) * P1B] : E;
  rcnt[t] = 0; rsum[t] = 0.f;
  __syncthreads();
  for (int i = base + t; i < end; i += 256) {
    int2 p = bedge[i];
    int rlo = ((unsigned)p.x) >> 24;
    atomicAdd(&rcnt[rlo], 1);
    atomicAdd(&rsum[rlo], __int_as_float(p.y));
  }
  __syncthreads();
  int v = rcnt[t];
  tmp[t] = v;
  __syncthreads();
  for (int off = 1; off < 256; off <<= 1) {
    int u = (t >= off) ? tmp[t - off] : 0;
    __syncthreads();
    tmp[t] += u;
    __syncthreads();
  }
  rbase[t] = tmp[t] - v;                       // exclusive within bucket
  int r = (kb << BKT_SH) + t;
  if (r < N) { row_start[r] = base + rbase[t]; rowsum[r] = rsum[t]; }
  __syncthreads();
  rcnt[t] = rbase[t];                          // reuse as cursor
  __syncthreads();
  for (int i = base + t; i < end; i += 256) {
    int2 p = bedge[i];
    int rlo = ((unsigned)p.x) >> 24;
    int pos = base + atomicAdd(&rcnt[rlo], 1);
    pairs[pos] = make_int2(p.x & 0xFFFFFF, p.y);
  }
}

// ---------- d^{-1/2} in place ----------
__global__ void dis_k(float* __restrict__ rowsum, int n) {
  int i = blockIdx.x * 256 + threadIdx.x;
  if (i < n) {
    float s = rowsum[i];
    rowsum[i] = (s > 0.0f) ? rsqrtf(s) : 0.0f;
  }
}

// ---------- covered mask + row_start[N] terminator ----------
__global__ void covered_k(const int* __restrict__ index, int* __restrict__ covered,
                          int* __restrict__ row_start, int E, int n) {
  int i = blockIdx.x * 256 + threadIdx.x;
  if (i == 0) row_start[n] = E;
  if (i < n) covered[index[i]] = 1;
}

// ---------- scale pair values by dis[col] ----------
__global__ void scale_k(int2* __restrict__ pairs, const float* __restrict__ dis, int E) {
  int i = blockIdx.x * 256 + threadIdx.x;
  if (i < E) {
    int2 p = pairs[i];
    p.y = __float_as_int(__int_as_float(p.y) * dis[p.x]);
    pairs[i] = p;
  }
}

// ---------- shared SpMM row body ----------
#define SPMM_BODY(HSRC)                                                        \
  float ax0 = 0.f, ay0 = 0.f, ax1 = 0.f, ay1 = 0.f;                            \
  for (int base = beg; base < end; base += 64) {                               \
    int m = end - base; if (m > 64) m = 64;                                    \
    int2 p = make_int2(0, 0);                                                  \
    if (base + lane < end) p = pairs[base + lane];                             \
    int pc = p.x; float pv = __int_as_float(p.y);                              \
    int j = 0;                                                                 \
    for (; j + 4 <= m; j += 4) {                                               \
      int   c0 = __shfl(pc, j),     c1 = __shfl(pc, j + 1);                    \
      int   c2 = __shfl(pc, j + 2), c3 = __shfl(pc, j + 3);                    \
      float v0 = __shfl(pv, j),     v1 = __shfl(pv, j + 1);                    \
      float v2 = __shfl(pv, j + 2), v3 = __shfl(pv, j + 3);                    \
      unsigned g0 = HSRC[(size_t)c0 * 64 + lane];                              \
      unsigned g1 = HSRC[(size_t)c1 * 64 + lane];                              \
      unsigned g2 = HSRC[(size_t)c2 * 64 + lane];                              \
      unsigned g3 = HSRC[(size_t)c3 * 64 + lane];                              \
      ax0 = fmaf(v0, bf_lo(g0), ax0); ay0 = fmaf(v0, bf_hi(g0), ay0);          \
      ax1 = fmaf(v1, bf_lo(g1), ax1); ay1 = fmaf(v1, bf_hi(g1), ay1);          \
      ax0 = fmaf(v2, bf_lo(g2), ax0); ay0 = fmaf(v2, bf_hi(g2), ay0);          \
      ax1 = fmaf(v3, bf_lo(g3), ax1); ay1 = fmaf(v3, bf_hi(g3), ay1);          \
    }                                                                          \
    for (; j < m; ++j) {                                                       \
      int c = __shfl(pc, j); float v = __shfl(pv, j);                          \
      unsigned g = HSRC[(size_t)c * 64 + lane];                                \
      ax0 = fmaf(v, bf_lo(g), ax0); ay0 = fmaf(v, bf_hi(g), ay0);              \
    }                                                                          \
  }

// ---------- layer 1: hA[index[r]] = bf16( dis[r] * sum vals*hB[col] ) ----------
__global__ void spmm1_k(const int* __restrict__ row_start, const int2* __restrict__ pairs,
                        const float* __restrict__ dis, const unsigned* __restrict__ hB,
                        const int* __restrict__ index, unsigned* __restrict__ hA, int n) {
  int wave = blockIdx.x * WPB + (threadIdx.x >> 6);
  if (wave >= n) return;
  int lane = threadIdx.x & 63;
  int beg = row_start[wave], end = row_start[wave + 1];
  SPMM_BODY(hB)
  float dr = dis[wave];
  float x = (ax0 + ax1) * dr, y = (ay0 + ay1) * dr;
  hA[(size_t)index[wave] * 64 + lane] = bf16rne(x) | (bf16rne(y) << 16);
}

// ---------- layer 2 fused epilogue: out[o] = a0*f[o] + a1*hA[o] + a2*acc ----------
__global__ void spmm2_k(const int* __restrict__ row_start, const int2* __restrict__ pairs,
                        const float* __restrict__ dis, const unsigned* __restrict__ hA,
                        const int* __restrict__ index, const float2* __restrict__ feat,
                        float2* __restrict__ out, const float* __restrict__ a, int n) {
  int wave = blockIdx.x * WPB + (threadIdx.x >> 6);
  if (wave >= n) return;
  int lane = threadIdx.x & 63;
  int beg = row_start[wave], end = row_start[wave + 1];
  SPMM_BODY(hA)
  float dr = dis[wave];
  float hx = (ax0 + ax1) * dr, hy = (ay0 + ay1) * dr;
  size_t o = (size_t)index[wave] * 64 + lane;
  unsigned g = hA[o];
  float2 f = feat[o];
  float a0 = a[0], a1 = a[1], a2 = a[2];
  out[o] = make_float2(fmaf(a2, hx, fmaf(a1, bf_lo(g), a0 * f.x)),
                       fmaf(a2, hy, fmaf(a1, bf_hi(g), a0 * f.y)));
}

// ---------- fixups for uncovered nodes (no-op when index is a permutation) ----------
__global__ void fixup1_k(const int* __restrict__ covered, const unsigned* __restrict__ hB,
                         unsigned* __restrict__ hA, int n) {
  int v = blockIdx.x * 256 + threadIdx.x;
  if (v >= n || covered[v]) return;
  for (int d = 0; d < 64; ++d) hA[(size_t)v * 64 + d] = hB[(size_t)v * 64 + d];
}

__global__ void fixup2_k(const int* __restrict__ covered, const float2* __restrict__ feat,
                         float2* __restrict__ out, const float* __restrict__ a, int n) {
  int v = blockIdx.x * 256 + threadIdx.x;
  if (v >= n || covered[v]) return;
  float s = a[0] + a[1] + a[2];
  for (int d = 0; d < 64; ++d) {
    float2 f = feat[(size_t)v * 64 + d];
    out[(size_t)v * 64 + d] = make_float2(s * f.x, s * f.y);
  }
}

extern "C" void kernel_launch(void* const* d_in, const int* in_sizes, int n_in,
                              void* d_out, int out_size, void* d_ws, size_t ws_size,
                              hipStream_t stream) {
  const float* features = (const float*)d_in[0];
  const int*   edge_row = (const int*)d_in[1];
  const int*   edge_col = (const int*)d_in[2];
  const float* edge_val = (const float*)d_in[3];
  const int*   index    = (const int*)d_in[4];
  const float* a_in     = (const float*)d_in[5];

  const int E = in_sizes[1];
  const int N = in_sizes[4];
  const int NB = (N + 255) >> BKT_SH;          // buckets of 256 rows
  const int NBH = NB * P1B;                    // (bucket, block) table size
  const int C = (E + P1B - 1) / P1B;           // edges per bucketing block

  float* out = (float*)d_out;

  // ---- workspace carve (256B aligned) ----
  char* ws = (char*)d_ws;
  size_t off = 0;
  auto carve = [&](size_t bytes) -> char* {
    char* p = ws + off;
    off = (off + bytes + 255) & ~(size_t)255;
    return p;
  };
  float* a_buf     = (float*)carve(16 * sizeof(float));
  float* rowsum    = (float*)carve((size_t)N * 4);          // becomes dis
  int*   covered   = (int*)carve((size_t)N * 4);
  int*   row_start = (int*)carve((size_t)(N + 1) * 4);
  int*   bsum      = (int*)carve(256 * 4);
  int2*  pairs     = (int2*)carve((size_t)E * 8);
  unsigned* hB     = (unsigned*)carve((size_t)N * 64 * 4);  // bf16 features
  // overlay region: bhist|boffs|bedge live only during CSR build; hA after
  size_t ov_bytes = (size_t)NBH * 4 * 2 + (size_t)E * 8 + 1024;
  size_t hA_bytes = (size_t)N * 64 * 4;
  char* ovl = carve(ov_bytes > hA_bytes ? ov_bytes : hA_bytes);
  int*  bhist = (int*)ovl;
  int*  boffs = (int*)(ovl + (((size_t)NBH * 4 + 255) & ~(size_t)255));
  int2* bedge = (int2*)(ovl + 2 * (((size_t)NBH * 4 + 255) & ~(size_t)255));
  unsigned* hA = (unsigned*)ovl;
  (void)ws_size; (void)n_in; (void)out_size;

  const int nbE = (E + 255) / 256;
  const int nbW = (N * 64 + 255) / 256;
  const int nbScan = (NBH + SCAN_B - 1) / SCAN_B;
  const int nbN = (N + 255) / 256;
  const size_t ldsB = (size_t)NB * 4;

  hipMemsetAsync(covered, 0, (size_t)N * 4, stream);
  softmax3_k<<<1, 64, 0, stream>>>(a_in, a_buf);
  tobf16_k<<<nbW, 256, 0, stream>>>((const float2*)features, hB, N * 64);
  p1_k<<<P1B, 256, ldsB, stream>>>(edge_row, bhist, E, C, NB);
  scanA_k<<<nbScan, SCAN_B, 0, stream>>>(bhist, boffs, bsum, NBH);
  scanB_k<<<1, 128, 0, stream>>>(bsum, nbScan);
  scanC_k<<<nbScan, SCAN_B, 0, stream>>>(boffs, bhist, bsum, NBH);
  p2_k<<<P1B, 256, ldsB, stream>>>(edge_row, edge_col, edge_val, boffs, bedge, E, C, NB);
  p3_k<<<NB, 256, 0, stream>>>(bedge, boffs, row_start, rowsum, pairs, E, N, NB);
  dis_k<<<nbN, 256, 0, stream>>>(rowsum, N);
  covered_k<<<nbN, 256, 0, stream>>>(index, covered, row_start, E, N);
  scale_k<<<nbE, 256, 0, stream>>>(pairs, rowsum, E);

  const int nbSpmm = (N + WPB - 1) / WPB;
  spmm1_k<<<nbSpmm, WPB * 64, 0, stream>>>(row_start, pairs, rowsum, hB, index, hA, N);
  fixup1_k<<<nbN, 256, 0, stream>>>(covered, hB, hA, N);
  spmm2_k<<<nbSpmm, WPB * 64, 0, stream>>>(row_start, pairs, rowsum, hA, index,
                                           (const float2*)features, (float2*)out,
                                           a_buf, N);
  fixup2_k<<<nbN, 256, 0, stream>>>(covered, (const float2*)features,
                                    (float2*)out, a_buf, N);
}

// Round 4
// 218.968 us; speedup vs baseline: 2.8119x; 1.0763x over previous
//
#include <hip/hip_runtime.h>

#define WPB    4         // waves per block in spmm (256 threads)
#define SCAN_B 1024
#define P1B    256       // blocks in bucketing passes
#define BKT_SH 8         // 256 rows per bucket

// ---------- bf16 helpers ----------
__device__ __forceinline__ unsigned bf16rne(float x) {
  unsigned u = __float_as_uint(x);
  return (u + 0x7fffu + ((u >> 16) & 1u)) >> 16;
}
__device__ __forceinline__ float bf_lo(unsigned g) { return __uint_as_float(g << 16); }
__device__ __forceinline__ float bf_hi(unsigned g) { return __uint_as_float(g & 0xffff0000u); }

// ---------- prep: bf16 feature table + covered mask + softmax + terminator ----------
__global__ void prep_k(const float2* __restrict__ f, unsigned* __restrict__ hb, int nw,
                       const float* __restrict__ a_in, float* __restrict__ a_buf,
                       const int* __restrict__ index, int* __restrict__ covered,
                       int* __restrict__ row_start, int E, int N) {
  int i = blockIdx.x * 256 + threadIdx.x;
  if (i < nw) {
    float2 v = f[i];
    hb[i] = bf16rne(v.x) | (bf16rne(v.y) << 16);
  }
  if (i < N) covered[index[i]] = 1;
  if (i == 0) {
    row_start[N] = E;
    float x0 = a_in[0], x1 = a_in[1], x2 = a_in[2];
    float m = fmaxf(x0, fmaxf(x1, x2));
    float e0 = expf(x0 - m), e1 = expf(x1 - m), e2 = expf(x2 - m);
    float s = e0 + e1 + e2;
    a_buf[0] = e0 / s; a_buf[1] = e1 / s; a_buf[2] = e2 / s;
  }
}

// ---------- pass 1: per-(bucket,block) edge histogram, LDS atomics only ----------
__global__ void p1_k(const int* __restrict__ row, int* __restrict__ bhist,
                     int E, int C, int NB) {
  extern __shared__ int h[];
  for (int k = threadIdx.x; k < NB; k += 256) h[k] = 0;
  __syncthreads();
  int s = blockIdx.x * C, e = min(E, s + C);
  for (int i = s + threadIdx.x; i < e; i += 256)
    atomicAdd(&h[row[i] >> BKT_SH], 1);
  __syncthreads();
  for (int k = threadIdx.x; k < NB; k += 256)
    bhist[(size_t)k * P1B + blockIdx.x] = h[k];
}

// ---------- scan stage A over bhist ----------
__global__ void scanA_k(const int* __restrict__ cnt, int* __restrict__ incl,
                        int* __restrict__ bsum, int n) {
  __shared__ int tmp[SCAN_B];
  int tid = threadIdx.x;
  int g = blockIdx.x * SCAN_B + tid;
  tmp[tid] = (g < n) ? cnt[g] : 0;
  __syncthreads();
  for (int off = 1; off < SCAN_B; off <<= 1) {
    int t = (tid >= off) ? tmp[tid - off] : 0;
    __syncthreads();
    tmp[tid] += t;
    __syncthreads();
  }
  if (g < n) incl[g] = tmp[tid];
  if (tid == SCAN_B - 1) bsum[blockIdx.x] = tmp[tid];
}

// ---------- scan stage B (single block, nb <= 128) ----------
__global__ void scanB_k(int* __restrict__ bsum, int nb) {
  __shared__ int tmp[128];
  int tid = threadIdx.x;
  tmp[tid] = (tid < nb) ? bsum[tid] : 0;
  __syncthreads();
  for (int off = 1; off < 128; off <<= 1) {
    int t = (tid >= off) ? tmp[tid - off] : 0;
    __syncthreads();
    tmp[tid] += t;
    __syncthreads();
  }
  if (tid < nb) bsum[tid] = tmp[tid];
}

// ---------- scan stage C: boffs <- exclusive (in place over incl) ----------
__global__ void scanC_k(int* __restrict__ boffs, const int* __restrict__ bhist,
                        const int* __restrict__ bsum, int n) {
  int g = blockIdx.x * SCAN_B + threadIdx.x;
  if (g >= n) return;
  int off = (blockIdx.x > 0) ? bsum[blockIdx.x - 1] : 0;
  boffs[g] = boffs[g] + off - bhist[g];
}

// ---------- pass 2: scatter edges into bucket-grouped order (LDS cursors) ----------
__global__ void p2_k(const int* __restrict__ row, const int* __restrict__ col,
                     const float* __restrict__ val, const int* __restrict__ boffs,
                     int2* __restrict__ bedge, int E, int C, int NB) {
  extern __shared__ int cur[];
  for (int k = threadIdx.x; k < NB; k += 256)
    cur[k] = boffs[(size_t)k * P1B + blockIdx.x];
  __syncthreads();
  int s = blockIdx.x * C, e = min(E, s + C);
  for (int i = s + threadIdx.x; i < e; i += 256) {
    int r = row[i];
    int p = atomicAdd(&cur[r >> BKT_SH], 1);
    bedge[p] = make_int2(((r & 255) << 24) | col[i], __float_as_int(val[i]));
  }
}

// ---------- pass 3: per-bucket counting sort by row + rowsum -> dis + row_start ----------
__global__ void p3_k(const int2* __restrict__ bedge, const int* __restrict__ boffs,
                     int* __restrict__ row_start, float* __restrict__ dis,
                     int2* __restrict__ pairs, int E, int N, int NB) {
  __shared__ int rcnt[256];
  __shared__ float rsum[256];
  __shared__ int rbase[256];
  __shared__ int tmp[256];
  int kb = blockIdx.x, t = threadIdx.x;
  int base = boffs[(size_t)kb * P1B];
  int end  = (kb + 1 < NB) ? boffs[(size_t)(kb + 1) * P1B] : E;
  rcnt[t] = 0; rsum[t] = 0.f;
  __syncthreads();
  for (int i = base + t; i < end; i += 256) {
    int2 p = bedge[i];
    int rlo = ((unsigned)p.x) >> 24;
    atomicAdd(&rcnt[rlo], 1);
    atomicAdd(&rsum[rlo], __int_as_float(p.y));
  }
  __syncthreads();
  int v = rcnt[t];
  tmp[t] = v;
  __syncthreads();
  for (int off = 1; off < 256; off <<= 1) {
    int u = (t >= off) ? tmp[t - off] : 0;
    __syncthreads();
    tmp[t] += u;
    __syncthreads();
  }
  rbase[t] = tmp[t] - v;                       // exclusive within bucket
  int r = (kb << BKT_SH) + t;
  if (r < N) {
    row_start[r] = base + rbase[t];
    float s = rsum[t];
    dis[r] = (s > 0.0f) ? rsqrtf(s) : 0.0f;    // d^{-1/2} fused here
  }
  __syncthreads();
  rcnt[t] = rbase[t];                          // reuse as cursor
  __syncthreads();
  for (int i = base + t; i < end; i += 256) {
    int2 p = bedge[i];
    int rlo = ((unsigned)p.x) >> 24;
    int pos = base + atomicAdd(&rcnt[rlo], 1);
    pairs[pos] = make_int2(p.x & 0xFFFFFF, p.y);
  }
}

// ---------- scale pair values by dis[col] ----------
__global__ void scale_k(int2* __restrict__ pairs, const float* __restrict__ dis, int E) {
  int i = blockIdx.x * 256 + threadIdx.x;
  if (i < E) {
    int2 p = pairs[i];
    p.y = __float_as_int(__int_as_float(p.y) * dis[p.x]);
    pairs[i] = p;
  }
}

// ---------- quarter-wave SpMM body: 16 lanes/edge, uint4 gathers (8 bf16/lane) ----------
__device__ __forceinline__ void acc8(float v, uint4 g, float* a) {
  a[0] = fmaf(v, bf_lo(g.x), a[0]); a[1] = fmaf(v, bf_hi(g.x), a[1]);
  a[2] = fmaf(v, bf_lo(g.y), a[2]); a[3] = fmaf(v, bf_hi(g.y), a[3]);
  a[4] = fmaf(v, bf_lo(g.z), a[4]); a[5] = fmaf(v, bf_hi(g.z), a[5]);
  a[6] = fmaf(v, bf_lo(g.w), a[6]); a[7] = fmaf(v, bf_hi(g.w), a[7]);
}

__device__ __forceinline__ void spmm_body(const int* __restrict__ row_start,
                                          const int2* __restrict__ pairs,
                                          const uint4* __restrict__ h4,
                                          int wave, int lane, float* a) {
  int q = lane >> 4, ql = lane & 15;
  int beg = row_start[wave], end = row_start[wave + 1];
  for (int base = beg; base < end; base += 64) {
    int2 p = make_int2(0, 0);
    if (base + lane < end) p = pairs[base + lane];
    int pc = p.x; float pv = __int_as_float(p.y);
    int m = end - base; if (m > 64) m = 64;
    for (int j = 0; j < m; j += 16) {
      int   c0 = __shfl(pc, j + q),      c1 = __shfl(pc, j + 4 + q);
      int   c2 = __shfl(pc, j + 8 + q),  c3 = __shfl(pc, j + 12 + q);
      float v0 = __shfl(pv, j + q),      v1 = __shfl(pv, j + 4 + q);
      float v2 = __shfl(pv, j + 8 + q),  v3 = __shfl(pv, j + 12 + q);
      uint4 g0 = h4[(size_t)c0 * 16 + ql];
      uint4 g1 = h4[(size_t)c1 * 16 + ql];
      uint4 g2 = h4[(size_t)c2 * 16 + ql];
      uint4 g3 = h4[(size_t)c3 * 16 + ql];
      acc8(v0, g0, a); acc8(v1, g1, a);
      acc8(v2, g2, a); acc8(v3, g3, a);
    }
  }
#pragma unroll
  for (int i = 0; i < 8; ++i) a[i] += __shfl_xor(a[i], 16);
#pragma unroll
  for (int i = 0; i < 8; ++i) a[i] += __shfl_xor(a[i], 32);
}

// ---------- layer 1: hA[index[r]] = bf16( dis[r] * sum vals*hB[col] ) ----------
__global__ void spmm1_k(const int* __restrict__ row_start, const int2* __restrict__ pairs,
                        const float* __restrict__ dis, const uint4* __restrict__ hB4,
                        const int* __restrict__ index, uint4* __restrict__ hA4, int n) {
  int wave = blockIdx.x * WPB + (threadIdx.x >> 6);
  if (wave >= n) return;
  int lane = threadIdx.x & 63;
  float a[8] = {0.f, 0.f, 0.f, 0.f, 0.f, 0.f, 0.f, 0.f};
  spmm_body(row_start, pairs, hB4, wave, lane, a);
  if ((lane >> 4) == 0) {
    float dr = dis[wave];
    uint4 pk;
    pk.x = bf16rne(a[0] * dr) | (bf16rne(a[1] * dr) << 16);
    pk.y = bf16rne(a[2] * dr) | (bf16rne(a[3] * dr) << 16);
    pk.z = bf16rne(a[4] * dr) | (bf16rne(a[5] * dr) << 16);
    pk.w = bf16rne(a[6] * dr) | (bf16rne(a[7] * dr) << 16);
    hA4[(size_t)index[wave] * 16 + (lane & 15)] = pk;
  }
}

// ---------- layer 2 fused epilogue: out[o] = a0*f[o] + a1*hA[o] + a2*acc ----------
__global__ void spmm2_k(const int* __restrict__ row_start, const int2* __restrict__ pairs,
                        const float* __restrict__ dis, const uint4* __restrict__ hA4,
                        const uint4* __restrict__ hB4, const int* __restrict__ index,
                        float4* __restrict__ out4, const float* __restrict__ ac, int n) {
  int wave = blockIdx.x * WPB + (threadIdx.x >> 6);
  if (wave >= n) return;
  int lane = threadIdx.x & 63;
  float a[8] = {0.f, 0.f, 0.f, 0.f, 0.f, 0.f, 0.f, 0.f};
  spmm_body(row_start, pairs, hA4, wave, lane, a);
  if ((lane >> 4) == 0) {
    int ql = lane & 15;
    float dr = dis[wave];
    size_t ro = (size_t)index[wave] * 16 + ql;
    uint4 ga = hA4[ro];
    uint4 gb = hB4[ro];
    float c0 = ac[0], c1 = ac[1], c2 = ac[2];
    float4 w0, w1;
    w0.x = fmaf(c2, a[0] * dr, fmaf(c1, bf_lo(ga.x), c0 * bf_lo(gb.x)));
    w0.y = fmaf(c2, a[1] * dr, fmaf(c1, bf_hi(ga.x), c0 * bf_hi(gb.x)));
    w0.z = fmaf(c2, a[2] * dr, fmaf(c1, bf_lo(ga.y), c0 * bf_lo(gb.y)));
    w0.w = fmaf(c2, a[3] * dr, fmaf(c1, bf_hi(ga.y), c0 * bf_hi(gb.y)));
    w1.x = fmaf(c2, a[4] * dr, fmaf(c1, bf_lo(ga.z), c0 * bf_lo(gb.z)));
    w1.y = fmaf(c2, a[5] * dr, fmaf(c1, bf_hi(ga.z), c0 * bf_hi(gb.z)));
    w1.z = fmaf(c2, a[6] * dr, fmaf(c1, bf_lo(ga.w), c0 * bf_lo(gb.w)));
    w1.w = fmaf(c2, a[7] * dr, fmaf(c1, bf_hi(ga.w), c0 * bf_hi(gb.w)));
    out4[(size_t)index[wave] * 32 + 2 * ql]     = w0;
    out4[(size_t)index[wave] * 32 + 2 * ql + 1] = w1;
  }
}

// ---------- fixups for uncovered nodes (no-op when index is a permutation) ----------
__global__ void fixup1_k(const int* __restrict__ covered, const uint4* __restrict__ hB4,
                         uint4* __restrict__ hA4, int n) {
  int v = blockIdx.x * 256 + threadIdx.x;
  if (v >= n || covered[v]) return;
  for (int d = 0; d < 16; ++d) hA4[(size_t)v * 16 + d] = hB4[(size_t)v * 16 + d];
}

__global__ void fixup2_k(const int* __restrict__ covered, const float2* __restrict__ feat,
                         float2* __restrict__ out, const float* __restrict__ a, int n) {
  int v = blockIdx.x * 256 + threadIdx.x;
  if (v >= n || covered[v]) return;
  float s = a[0] + a[1] + a[2];
  for (int d = 0; d < 64; ++d) {
    float2 f = feat[(size_t)v * 64 + d];
    out[(size_t)v * 64 + d] = make_float2(s * f.x, s * f.y);
  }
}

extern "C" void kernel_launch(void* const* d_in, const int* in_sizes, int n_in,
                              void* d_out, int out_size, void* d_ws, size_t ws_size,
                              hipStream_t stream) {
  const float* features = (const float*)d_in[0];
  const int*   edge_row = (const int*)d_in[1];
  const int*   edge_col = (const int*)d_in[2];
  const float* edge_val = (const float*)d_in[3];
  const int*   index    = (const int*)d_in[4];
  const float* a_in     = (const float*)d_in[5];

  const int E = in_sizes[1];
  const int N = in_sizes[4];
  const int NB = (N + 255) >> BKT_SH;          // buckets of 256 rows
  const int NBH = NB * P1B;                    // (bucket, block) table size
  const int C = (E + P1B - 1) / P1B;           // edges per bucketing block

  float* out = (float*)d_out;

  // ---- workspace carve (256B aligned) ----
  char* ws = (char*)d_ws;
  size_t off = 0;
  auto carve = [&](size_t bytes) -> char* {
    char* p = ws + off;
    off = (off + bytes + 255) & ~(size_t)255;
    return p;
  };
  float* a_buf     = (float*)carve(16 * sizeof(float));
  float* dis       = (float*)carve((size_t)N * 4);
  int*   covered   = (int*)carve((size_t)N * 4);
  int*   row_start = (int*)carve((size_t)(N + 1) * 4);
  int*   bsum      = (int*)carve(256 * 4);
  int2*  pairs     = (int2*)carve((size_t)E * 8);
  unsigned* hB     = (unsigned*)carve((size_t)N * 64 * 4);  // bf16 features
  // overlay region: bhist|boffs|bedge live only during CSR build; hA after
  size_t ov_bytes = (size_t)NBH * 4 * 2 + (size_t)E * 8 + 1024;
  size_t hA_bytes = (size_t)N * 64 * 4;
  char* ovl = carve(ov_bytes > hA_bytes ? ov_bytes : hA_bytes);
  int*  bhist = (int*)ovl;
  int*  boffs = (int*)(ovl + (((size_t)NBH * 4 + 255) & ~(size_t)255));
  int2* bedge = (int2*)(ovl + 2 * (((size_t)NBH * 4 + 255) & ~(size_t)255));
  unsigned* hA = (unsigned*)ovl;
  (void)ws_size; (void)n_in; (void)out_size;

  const int nbE = (E + 255) / 256;
  const int nbW = (N * 64 + 255) / 256;
  const int nbScan = (NBH + SCAN_B - 1) / SCAN_B;
  const int nbN = (N + 255) / 256;
  const size_t ldsB = (size_t)NB * 4;

  hipMemsetAsync(covered, 0, (size_t)N * 4, stream);
  prep_k<<<nbW, 256, 0, stream>>>((const float2*)features, hB, N * 64,
                                  a_in, a_buf, index, covered, row_start, E, N);
  p1_k<<<P1B, 256, ldsB, stream>>>(edge_row, bhist, E, C, NB);
  scanA_k<<<nbScan, SCAN_B, 0, stream>>>(bhist, boffs, bsum, NBH);
  scanB_k<<<1, 128, 0, stream>>>(bsum, nbScan);
  scanC_k<<<nbScan, SCAN_B, 0, stream>>>(boffs, bhist, bsum, NBH);
  p2_k<<<P1B, 256, ldsB, stream>>>(edge_row, edge_col, edge_val, boffs, bedge, E, C, NB);
  p3_k<<<NB, 256, 0, stream>>>(bedge, boffs, row_start, dis, pairs, E, N, NB);
  scale_k<<<nbE, 256, 0, stream>>>(pairs, dis, E);

  const int nbSpmm = (N + WPB - 1) / WPB;
  spmm1_k<<<nbSpmm, WPB * 64, 0, stream>>>(row_start, pairs, dis, (const uint4*)hB,
                                           index, (uint4*)hA, N);
  fixup1_k<<<nbN, 256, 0, stream>>>(covered, (const uint4*)hB, (uint4*)hA, N);
  spmm2_k<<<nbSpmm, WPB * 64, 0, stream>>>(row_start, pairs, dis, (const uint4*)hA,
                                           (const uint4*)hB, index, (float4*)out,
                                           a_buf, N);
  fixup2_k<<<nbN, 256, 0, stream>>>(covered, (const float2*)features,
                                    (float2*)out, a_buf, N);
}

// Round 5
// 212.811 us; speedup vs baseline: 2.8933x; 1.0289x over previous
//
#include <hip/hip_runtime.h>

#define WPB    4         // waves per block in spmm (256 threads)
#define SCAN_B 1024
#define P1B    256       // blocks in bucketing passes
#define BKT_SH 8         // 256 rows per bucket

typedef unsigned u32x4 __attribute__((ext_vector_type(4)));
typedef float    f32x4 __attribute__((ext_vector_type(4)));
typedef float    f32x2 __attribute__((ext_vector_type(2)));

// ---------- bf16 helpers ----------
__device__ __forceinline__ unsigned bf16rne(float x) {
  unsigned u = __float_as_uint(x);
  return (u + 0x7fffu + ((u >> 16) & 1u)) >> 16;
}
__device__ __forceinline__ float bf_lo(unsigned g) { return __uint_as_float(g << 16); }
__device__ __forceinline__ float bf_hi(unsigned g) { return __uint_as_float(g & 0xffff0000u); }

// ---------- fused prep (bf16 table + covered + softmax + terminator) + p1 histogram ----------
__global__ void prep_p1_k(const f32x2* __restrict__ f, unsigned* __restrict__ hb, int nw,
                          const float* __restrict__ a_in, float* __restrict__ a_buf,
                          const int* __restrict__ index, int* __restrict__ covered,
                          int* __restrict__ row_start, const int* __restrict__ erow,
                          int* __restrict__ bhist, int E, int N, int C, int NB) {
  extern __shared__ int h[];
  const bool dop1 = (blockIdx.x < P1B);
  if (dop1) {
    for (int k = threadIdx.x; k < NB; k += 256) h[k] = 0;
    __syncthreads();
  }
  int i = blockIdx.x * 256 + threadIdx.x;
  if (i < nw) {
    f32x2 v = __builtin_nontemporal_load(f + i);
    hb[i] = bf16rne(v.x) | (bf16rne(v.y) << 16);
  }
  if (i < N) covered[index[i]] = 1;
  if (i == 0) {
    row_start[N] = E;
    float x0 = a_in[0], x1 = a_in[1], x2 = a_in[2];
    float m = fmaxf(x0, fmaxf(x1, x2));
    float e0 = expf(x0 - m), e1 = expf(x1 - m), e2 = expf(x2 - m);
    float s = e0 + e1 + e2;
    a_buf[0] = e0 / s; a_buf[1] = e1 / s; a_buf[2] = e2 / s;
  }
  if (dop1) {
    int s = blockIdx.x * C, e = min(E, s + C);
    for (int j = s + threadIdx.x; j < e; j += 256)
      atomicAdd(&h[erow[j] >> BKT_SH], 1);
    __syncthreads();
    for (int k = threadIdx.x; k < NB; k += 256)
      bhist[(size_t)k * P1B + blockIdx.x] = h[k];
  }
}

// ---------- scan stage A over bhist ----------
__global__ void scanA_k(const int* __restrict__ cnt, int* __restrict__ incl,
                        int* __restrict__ bsum, int n) {
  __shared__ int tmp[SCAN_B];
  int tid = threadIdx.x;
  int g = blockIdx.x * SCAN_B + tid;
  tmp[tid] = (g < n) ? cnt[g] : 0;
  __syncthreads();
  for (int off = 1; off < SCAN_B; off <<= 1) {
    int t = (tid >= off) ? tmp[tid - off] : 0;
    __syncthreads();
    tmp[tid] += t;
    __syncthreads();
  }
  if (g < n) incl[g] = tmp[tid];
  if (tid == SCAN_B - 1) bsum[blockIdx.x] = tmp[tid];
}

// ---------- scan stage B+C fused: each block redundantly scans bsum, finalizes boffs ----------
__global__ void scanBC_k(int* __restrict__ boffs, const int* __restrict__ bhist,
                         const int* __restrict__ bsum, int nb, int n) {
  __shared__ int bs[128];
  int tid = threadIdx.x;
  if (tid < 128) bs[tid] = (tid < nb) ? bsum[tid] : 0;
  __syncthreads();
  for (int off = 1; off < 128; off <<= 1) {
    int t = (tid >= off && tid < 128) ? bs[tid - off] : 0;
    __syncthreads();
    if (tid < 128) bs[tid] += t;
    __syncthreads();
  }
  int g = blockIdx.x * SCAN_B + tid;
  if (g < n) {
    int off2 = (blockIdx.x > 0) ? bs[blockIdx.x - 1] : 0;
    boffs[g] = boffs[g] + off2 - bhist[g];
  }
}

// ---------- pass 2: scatter edges into bucket-grouped order (LDS cursors) ----------
__global__ void p2_k(const int* __restrict__ row, const int* __restrict__ col,
                     const float* __restrict__ val, const int* __restrict__ boffs,
                     int2* __restrict__ bedge, int E, int C, int NB) {
  extern __shared__ int cur[];
  for (int k = threadIdx.x; k < NB; k += 256)
    cur[k] = boffs[(size_t)k * P1B + blockIdx.x];
  __syncthreads();
  int s = blockIdx.x * C, e = min(E, s + C);
  for (int i = s + threadIdx.x; i < e; i += 256) {
    int r = row[i];
    int p = atomicAdd(&cur[r >> BKT_SH], 1);
    bedge[p] = make_int2(((r & 255) << 24) | col[i], __float_as_int(val[i]));
  }
}

// ---------- pass 3: per-bucket counting sort by row + rowsum -> dis + row_start ----------
__global__ void p3_k(const int2* __restrict__ bedge, const int* __restrict__ boffs,
                     int* __restrict__ row_start, float* __restrict__ dis,
                     int2* __restrict__ pairs, int E, int N, int NB) {
  __shared__ int rcnt[256];
  __shared__ float rsum[256];
  __shared__ int rbase[256];
  __shared__ int tmp[256];
  int kb = blockIdx.x, t = threadIdx.x;
  int base = boffs[(size_t)kb * P1B];
  int end  = (kb + 1 < NB) ? boffs[(size_t)(kb + 1) * P1B] : E;
  rcnt[t] = 0; rsum[t] = 0.f;
  __syncthreads();
  for (int i = base + t; i < end; i += 256) {
    int2 p = bedge[i];
    int rlo = ((unsigned)p.x) >> 24;
    atomicAdd(&rcnt[rlo], 1);
    atomicAdd(&rsum[rlo], __int_as_float(p.y));
  }
  __syncthreads();
  int v = rcnt[t];
  tmp[t] = v;
  __syncthreads();
  for (int off = 1; off < 256; off <<= 1) {
    int u = (t >= off) ? tmp[t - off] : 0;
    __syncthreads();
    tmp[t] += u;
    __syncthreads();
  }
  rbase[t] = tmp[t] - v;
  int r = (kb << BKT_SH) + t;
  if (r < N) {
    row_start[r] = base + rbase[t];
    float s = rsum[t];
    dis[r] = (s > 0.0f) ? rsqrtf(s) : 0.0f;
  }
  __syncthreads();
  rcnt[t] = rbase[t];
  __syncthreads();
  for (int i = base + t; i < end; i += 256) {
    int2 p = bedge[i];
    int rlo = ((unsigned)p.x) >> 24;
    int pos = base + atomicAdd(&rcnt[rlo], 1);
    pairs[pos] = make_int2(p.x & 0xFFFFFF, p.y);
  }
}

// ---------- quarter-wave SpMM body: 16 lanes/edge, uint4 gathers, 32-bit addressing ----------
__device__ __forceinline__ void acc8(float v, u32x4 g, float* a) {
  a[0] = fmaf(v, bf_lo(g.x), a[0]); a[1] = fmaf(v, bf_hi(g.x), a[1]);
  a[2] = fmaf(v, bf_lo(g.y), a[2]); a[3] = fmaf(v, bf_hi(g.y), a[3]);
  a[4] = fmaf(v, bf_lo(g.z), a[4]); a[5] = fmaf(v, bf_hi(g.z), a[5]);
  a[6] = fmaf(v, bf_lo(g.w), a[6]); a[7] = fmaf(v, bf_hi(g.w), a[7]);
}

__device__ __forceinline__ void spmm_body(const int* __restrict__ row_start,
                                          const int2* __restrict__ pairs,
                                          const float* __restrict__ dis,
                                          const char* __restrict__ hb,
                                          int wave, int lane, float* a) {
  int q = lane >> 4;
  unsigned qoff = (unsigned)(lane & 15) << 4;
  int beg = row_start[wave], end = row_start[wave + 1];
  for (int base = beg; base < end; base += 64) {
    unsigned long long pl = 0;
    if (base + lane < end)
      pl = __builtin_nontemporal_load((const unsigned long long*)(pairs + base + lane));
    int pc = (int)(pl & 0xffffffffu);
    float pv = __uint_as_float((unsigned)(pl >> 32)) * dis[pc];
    int m = end - base; if (m > 64) m = 64;
    for (int j = 0; j < m; j += 16) {
      int   c0 = __shfl(pc, j + q),      c1 = __shfl(pc, j + 4 + q);
      int   c2 = __shfl(pc, j + 8 + q),  c3 = __shfl(pc, j + 12 + q);
      float v0 = __shfl(pv, j + q),      v1 = __shfl(pv, j + 4 + q);
      float v2 = __shfl(pv, j + 8 + q),  v3 = __shfl(pv, j + 12 + q);
      u32x4 g0 = *(const u32x4*)(hb + (((unsigned)c0 << 8) | qoff));
      u32x4 g1 = *(const u32x4*)(hb + (((unsigned)c1 << 8) | qoff));
      u32x4 g2 = *(const u32x4*)(hb + (((unsigned)c2 << 8) | qoff));
      u32x4 g3 = *(const u32x4*)(hb + (((unsigned)c3 << 8) | qoff));
      acc8(v0, g0, a); acc8(v1, g1, a);
      acc8(v2, g2, a); acc8(v3, g3, a);
    }
  }
#pragma unroll
  for (int i = 0; i < 8; ++i) a[i] += __shfl_xor(a[i], 16);
#pragma unroll
  for (int i = 0; i < 8; ++i) a[i] += __shfl_xor(a[i], 32);
}

// ---------- layer 1: hA[index[r]] = bf16( dis[r] * sum vals*hB[col] ) ----------
__global__ void spmm1_k(const int* __restrict__ row_start, const int2* __restrict__ pairs,
                        const float* __restrict__ dis, const unsigned* __restrict__ hB,
                        const int* __restrict__ index, u32x4* __restrict__ hA4, int n) {
  int wave = blockIdx.x * WPB + (threadIdx.x >> 6);
  if (wave >= n) return;
  int lane = threadIdx.x & 63;
  float a[8] = {0.f, 0.f, 0.f, 0.f, 0.f, 0.f, 0.f, 0.f};
  spmm_body(row_start, pairs, dis, (const char*)hB, wave, lane, a);
  if ((lane >> 4) == 0) {
    float dr = dis[wave];
    u32x4 pk;
    pk.x = bf16rne(a[0] * dr) | (bf16rne(a[1] * dr) << 16);
    pk.y = bf16rne(a[2] * dr) | (bf16rne(a[3] * dr) << 16);
    pk.z = bf16rne(a[4] * dr) | (bf16rne(a[5] * dr) << 16);
    pk.w = bf16rne(a[6] * dr) | (bf16rne(a[7] * dr) << 16);
    hA4[(unsigned)index[wave] * 16u + (unsigned)(lane & 15)] = pk;
  }
}

// ---------- layer 2 fused epilogue: out = a0*f + a1*hA + a2*acc ----------
__global__ void spmm2_k(const int* __restrict__ row_start, const int2* __restrict__ pairs,
                        const float* __restrict__ dis, const u32x4* __restrict__ hA4,
                        const u32x4* __restrict__ hB4, const int* __restrict__ index,
                        f32x4* __restrict__ out4, const float* __restrict__ ac, int n) {
  int wave = blockIdx.x * WPB + (threadIdx.x >> 6);
  if (wave >= n) return;
  int lane = threadIdx.x & 63;
  float a[8] = {0.f, 0.f, 0.f, 0.f, 0.f, 0.f, 0.f, 0.f};
  spmm_body(row_start, pairs, dis, (const char*)hA4, wave, lane, a);
  if ((lane >> 4) == 0) {
    unsigned ql = lane & 15;
    float dr = dis[wave];
    unsigned ro = (unsigned)index[wave] * 16u + ql;
    u32x4 ga = hA4[ro];
    u32x4 gb = __builtin_nontemporal_load(hB4 + ro);
    float c0 = ac[0], c1 = ac[1], c2 = ac[2];
    f32x4 w0, w1;
    w0.x = fmaf(c2, a[0] * dr, fmaf(c1, bf_lo(ga.x), c0 * bf_lo(gb.x)));
    w0.y = fmaf(c2, a[1] * dr, fmaf(c1, bf_hi(ga.x), c0 * bf_hi(gb.x)));
    w0.z = fmaf(c2, a[2] * dr, fmaf(c1, bf_lo(ga.y), c0 * bf_lo(gb.y)));
    w0.w = fmaf(c2, a[3] * dr, fmaf(c1, bf_hi(ga.y), c0 * bf_hi(gb.y)));
    w1.x = fmaf(c2, a[4] * dr, fmaf(c1, bf_lo(ga.z), c0 * bf_lo(gb.z)));
    w1.y = fmaf(c2, a[5] * dr, fmaf(c1, bf_hi(ga.z), c0 * bf_hi(gb.z)));
    w1.z = fmaf(c2, a[6] * dr, fmaf(c1, bf_lo(ga.w), c0 * bf_lo(gb.w)));
    w1.w = fmaf(c2, a[7] * dr, fmaf(c1, bf_hi(ga.w), c0 * bf_hi(gb.w)));
    unsigned ob = (unsigned)index[wave] * 32u + 2u * ql;
    __builtin_nontemporal_store(w0, out4 + ob);
    __builtin_nontemporal_store(w1, out4 + ob + 1);
  }
}

// ---------- fixups for uncovered nodes (no-op when index is a permutation) ----------
__global__ void fixup1_k(const int* __restrict__ covered, const u32x4* __restrict__ hB4,
                         u32x4* __restrict__ hA4, int n) {
  int v = blockIdx.x * 256 + threadIdx.x;
  if (v >= n || covered[v]) return;
  for (int d = 0; d < 16; ++d) hA4[(size_t)v * 16 + d] = hB4[(size_t)v * 16 + d];
}

__global__ void fixup2_k(const int* __restrict__ covered, const float2* __restrict__ feat,
                         float2* __restrict__ out, const float* __restrict__ a, int n) {
  int v = blockIdx.x * 256 + threadIdx.x;
  if (v >= n || covered[v]) return;
  float s = a[0] + a[1] + a[2];
  for (int d = 0; d < 64; ++d) {
    float2 f = feat[(size_t)v * 64 + d];
    out[(size_t)v * 64 + d] = make_float2(s * f.x, s * f.y);
  }
}

extern "C" void kernel_launch(void* const* d_in, const int* in_sizes, int n_in,
                              void* d_out, int out_size, void* d_ws, size_t ws_size,
                              hipStream_t stream) {
  const float* features = (const float*)d_in[0];
  const int*   edge_row = (const int*)d_in[1];
  const int*   edge_col = (const int*)d_in[2];
  const float* edge_val = (const float*)d_in[3];
  const int*   index    = (const int*)d_in[4];
  const float* a_in     = (const float*)d_in[5];

  const int E = in_sizes[1];
  const int N = in_sizes[4];
  const int NB = (N + 255) >> BKT_SH;
  const int NBH = NB * P1B;
  const int C = (E + P1B - 1) / P1B;

  float* out = (float*)d_out;

  char* ws = (char*)d_ws;
  size_t off = 0;
  auto carve = [&](size_t bytes) -> char* {
    char* p = ws + off;
    off = (off + bytes + 255) & ~(size_t)255;
    return p;
  };
  float* a_buf     = (float*)carve(16 * sizeof(float));
  float* dis       = (float*)carve((size_t)N * 4);
  int*   covered   = (int*)carve((size_t)N * 4);
  int*   row_start = (int*)carve((size_t)(N + 1) * 4);
  int*   bsum      = (int*)carve(256 * 4);
  int2*  pairs     = (int2*)carve((size_t)E * 8);
  unsigned* hB     = (unsigned*)carve((size_t)N * 64 * 4);
  size_t ov_bytes = (size_t)NBH * 4 * 2 + (size_t)E * 8 + 1024;
  size_t hA_bytes = (size_t)N * 64 * 4;
  char* ovl = carve(ov_bytes > hA_bytes ? ov_bytes : hA_bytes);
  int*  bhist = (int*)ovl;
  int*  boffs = (int*)(ovl + (((size_t)NBH * 4 + 255) & ~(size_t)255));
  int2* bedge = (int2*)(ovl + 2 * (((size_t)NBH * 4 + 255) & ~(size_t)255));
  unsigned* hA = (unsigned*)ovl;
  (void)ws_size; (void)n_in; (void)out_size;

  const int nbW = (N * 64 + 255) / 256;
  const int nbScan = (NBH + SCAN_B - 1) / SCAN_B;
  const int nbN = (N + 255) / 256;
  const size_t ldsB = (size_t)NB * 4;

  hipMemsetAsync(covered, 0, (size_t)N * 4, stream);
  prep_p1_k<<<nbW, 256, ldsB, stream>>>((const f32x2*)features, hB, N * 64,
                                        a_in, a_buf, index, covered, row_start,
                                        edge_row, bhist, E, N, C, NB);
  scanA_k<<<nbScan, SCAN_B, 0, stream>>>(bhist, boffs, bsum, NBH);
  scanBC_k<<<nbScan, SCAN_B, 0, stream>>>(boffs, bhist, bsum, nbScan, NBH);
  p2_k<<<P1B, 256, ldsB, stream>>>(edge_row, edge_col, edge_val, boffs, bedge, E, C, NB);
  p3_k<<<NB, 256, 0, stream>>>(bedge, boffs, row_start, dis, pairs, E, N, NB);

  const int nbSpmm = (N + WPB - 1) / WPB;
  spmm1_k<<<nbSpmm, WPB * 64, 0, stream>>>(row_start, pairs, dis, hB, index,
                                           (u32x4*)hA, N);
  fixup1_k<<<nbN, 256, 0, stream>>>(covered, (const u32x4*)hB, (u32x4*)hA, N);
  spmm2_k<<<nbSpmm, WPB * 64, 0, stream>>>(row_start, pairs, dis, (const u32x4*)hA,
                                           (const u32x4*)hB, index, (f32x4*)out,
                                           a_buf, N);
  fixup2_k<<<nbN, 256, 0, stream>>>(covered, (const float2*)features,
                                    (float2*)out, a_buf, N);
}